// Round 2
// baseline (1296.939 us; speedup 1.0000x reference)
//
#include <hip/hip_runtime.h>
#include <cmath>

// LabelSmoothing KL loss, decomposed (atomic-free, deterministic):
//   out = [ sum_{t!=0} (cterm - (b-a)*logp_t)  -  a*S_all  +  a*sum_{t==0} S_row ] / norm
// where S_all = sum of log p over ALL B*L*V elements (ignored rows added back).
//
// Kernel A: flat grid-stride float4 streaming reduce (the measured-6.3TB/s
//           pattern) over all B*L*V elements. No per-row structure, no tgt
//           reads, 2048 resident blocks, exact 125-trip compile-time loop.
//           Accumulates log2 (v_log_f32 IS log2); ln2 folded in later.
//           Writes one float partial per block to ws[0..2047].
// Kernel B: per-row target terms (8192 rows, 32 blocks) + rare cooperative
//           add-back of a*S_row for ignored rows (expected ~BL/V rows).
//           Writes one float partial per block to ws[2048..2048+NB-1].
// Kernel C: single-block double reduction of all partials, / norm, write out.

#define LS_LN2 0.6931471805599453094172321214581766

// ---------------- Kernel A: flat log2 sum -> per-block partials ----------------
template<int N4C, int STRIDE_C>
__global__ __launch_bounds__(256) void ls_flat_log2sum(
    const float* __restrict__ p,
    float*       __restrict__ partA,
    int n4_rt)
{
    const int n4     = (N4C      > 0) ? N4C      : n4_rt;
    const int stride = (STRIDE_C > 0) ? STRIDE_C : (int)(gridDim.x * blockDim.x);
    const float4* __restrict__ p4 = (const float4*)p;

    float s0 = 0.f, s1 = 0.f, s2 = 0.f, s3 = 0.f;
    #pragma unroll 5
    for (int i = blockIdx.x * 256 + threadIdx.x; i < n4; i += stride) {
        float4 v = p4[i];
        s0 += __log2f(v.x);
        s1 += __log2f(v.y);
        s2 += __log2f(v.z);
        s3 += __log2f(v.w);
    }
    float s = (s0 + s1) + (s2 + s3);

    #pragma unroll
    for (int off = 32; off > 0; off >>= 1)
        s += __shfl_down(s, off, 64);

    __shared__ float wsum[4];
    const int wid  = threadIdx.x >> 6;
    const int lane = threadIdx.x & 63;
    if (lane == 0) wsum[wid] = s;
    __syncthreads();
    if (threadIdx.x == 0)
        partA[blockIdx.x] = (wsum[0] + wsum[1]) + (wsum[2] + wsum[3]);
}

// ---------------- Kernel B: per-row terms + masked add-back ----------------
__global__ __launch_bounds__(256) void ls_row_terms(
    const float* __restrict__ p,
    const int*   __restrict__ tgt,
    float*       __restrict__ partB,
    float cterm, float bma, float a_ln2,
    int BL, int V)
{
    __shared__ int   masked[256];
    __shared__ int   nmaskS;
    __shared__ float wsum[4];
    if (threadIdx.x == 0) nmaskS = 0;
    __syncthreads();

    const int r = blockIdx.x * 256 + threadIdx.x;
    float my = 0.f;
    if (r < BL) {
        const int t = tgt[r];
        if (t != 0) {
            my = cterm - bma * __logf(p[(size_t)r * V + t]);
        } else {
            masked[atomicAdd(&nmaskS, 1)] = r;   // shared-mem atomic; rare
        }
    }
    __syncthreads();

    // Add back a*S_row for ignored rows (kernel A's S_all subtracted them).
    const int nm = nmaskS;
    for (int m = 0; m < nm; ++m) {
        const int row = masked[m];
        const float4* p4 = (const float4*)(p + (size_t)row * V);
        float s = 0.f;
        for (int i = threadIdx.x; i < (V >> 2); i += 256) {
            float4 v = p4[i];
            s += __log2f(v.x) + __log2f(v.y) + __log2f(v.z) + __log2f(v.w);
        }
        my += a_ln2 * s;
    }

    #pragma unroll
    for (int off = 32; off > 0; off >>= 1)
        my += __shfl_down(my, off, 64);
    const int wid  = threadIdx.x >> 6;
    const int lane = threadIdx.x & 63;
    if (lane == 0) wsum[wid] = my;
    __syncthreads();
    if (threadIdx.x == 0)
        partB[blockIdx.x] = (wsum[0] + wsum[1]) + (wsum[2] + wsum[3]);
}

// ---------------- Kernel C: final double reduction ----------------
__global__ __launch_bounds__(256) void ls_reduce_finalize(
    const float* __restrict__ partA, int nA, float neg_a_ln2,
    const float* __restrict__ partB, int nB,
    const int*   __restrict__ normp,
    float*       __restrict__ out)
{
    double s = 0.0;
    for (int i = threadIdx.x; i < nA; i += 256)
        s += (double)neg_a_ln2 * (double)partA[i];
    for (int i = threadIdx.x; i < nB; i += 256)
        s += (double)partB[i];

    #pragma unroll
    for (int off = 32; off > 0; off >>= 1)
        s += __shfl_down(s, off, 64);

    __shared__ double wsum[4];
    const int wid  = threadIdx.x >> 6;
    const int lane = threadIdx.x & 63;
    if (lane == 0) wsum[wid] = s;
    __syncthreads();
    if (threadIdx.x == 0) {
        double tot = ((wsum[0] + wsum[1]) + (wsum[2] + wsum[3]));
        const int   ni = normp[0];
        const float nf = (ni > 0 && ni < (1 << 30)) ? (float)ni : __int_as_float(ni);
        out[0] = (float)(tot / (double)nf);
    }
}

// ---------------- Legacy per-row kernel (generic fallback only) ----------------
template<int NV4>
__global__ __launch_bounds__(256) void ls_row_kernel(
    const float* __restrict__ p,
    const int*   __restrict__ tgt,
    const int*   __restrict__ normp,
    float*       __restrict__ out,
    float cterm, int V, int nv4_rt)
{
    const int row = blockIdx.x;
    const int tid = threadIdx.x;
    const int t   = tgt[row];
    if (t == 0) return;

    const float*  prow = p + (size_t)row * (size_t)V;
    const float4* p4   = (const float4*)prow;
    const int     nv4  = (NV4 > 0) ? NV4 : nv4_rt;

    float s0 = 0.f, s1 = 0.f, s2 = 0.f, s3 = 0.f;
    #pragma unroll 4
    for (int i = tid; i < nv4; i += 256) {
        float4 v = p4[i];
        s0 += __logf(v.x);
        s1 += __logf(v.y);
        s2 += __logf(v.z);
        s3 += __logf(v.w);
    }
    float s = (s0 + s1) + (s2 + s3);
    #pragma unroll
    for (int off = 32; off > 0; off >>= 1)
        s += __shfl_down(s, off, 64);

    __shared__ float wsum[4];
    const int wid  = tid >> 6;
    const int lane = tid & 63;
    if (lane == 0) wsum[wid] = s;
    __syncthreads();

    if (tid == 0) {
        float tot = (wsum[0] + wsum[1]) + (wsum[2] + wsum[3]);
        float lt  = __logf(prow[t]);
        const float a = 0.1f / (float)V;
        const float b = 1.0f - 0.1f + a;
        float loss = cterm - a * (tot - lt) - b * lt;
        int   ni = normp[0];
        float nf = (ni > 0 && ni < (1 << 30)) ? (float)ni : __int_as_float(ni);
        atomicAdd(out, loss / nf);
    }
}

extern "C" void kernel_launch(void* const* d_in, const int* in_sizes, int n_in,
                              void* d_out, int out_size, void* d_ws, size_t ws_size,
                              hipStream_t stream) {
    const float* p     = (const float*)d_in[0];
    const int*   tgt   = (const int*)d_in[1];
    const int*   normp = (const int*)d_in[2];
    float*       out   = (float*)d_out;

    const int BL = in_sizes[1];                 // B*L rows (8192)
    const int V  = in_sizes[0] / in_sizes[1];   // vocab (32000)

    const double a = 0.1 / (double)V;
    const double b = 1.0 - 0.1 + a;
    const float  cterm     = (float)(a * log(a) * (double)(V - 1) + b * log(b));
    const float  bma       = (float)(b - a);
    const float  a_ln2     = (float)(a * LS_LN2);
    const float  neg_a_ln2 = -a_ln2;

    const int       NA   = 2048;
    const int       NB   = (BL + 255) / 256;
    const long long n4ll = (long long)BL * (long long)(V >> 2);
    const size_t    need = (size_t)(NA + NB) * sizeof(float);

    if ((V & 3) == 0 && ws_size >= need && n4ll < (1LL << 31)) {
        float* partA = (float*)d_ws;
        float* partB = partA + NA;

        if (V == 32000 && BL == 8192) {
            // 65,536,000 float4 / (2048*256) threads = exactly 125 iters/thread.
            ls_flat_log2sum<65536000, 2048 * 256>
                <<<NA, 256, 0, stream>>>(p, partA, 0);
        } else {
            ls_flat_log2sum<0, 0>
                <<<NA, 256, 0, stream>>>(p, partA, (int)n4ll);
        }
        ls_row_terms<<<NB, 256, 0, stream>>>(
            p, tgt, partB, cterm, bma, a_ln2, BL, V);
        ls_reduce_finalize<<<1, 256, 0, stream>>>(
            partA, NA, neg_a_ln2, partB, NB, normp, out);
    } else {
        // Generic fallback: original per-row kernel (needs zeroed out).
        hipMemsetAsync(d_out, 0, sizeof(float), stream);
        ls_row_kernel<0><<<BL, 256, 0, stream>>>(p, tgt, normp, out, cterm, V, V >> 2);
    }
}